// Round 7
// baseline (1152.427 us; speedup 1.0000x reference)
//
#include <hip/hip_runtime.h>
#include <math.h>

// HungarianLoss: B=128 samples, each a 192x192 LSAP on
// cost[q][j] = -softmax(pred[q])[tgt[j]], then mean CE with matched classes.
//
// R7: capacitated dedup. Duplicate target classes give exactly-identical
// cost columns; the loss depends only on the row->CLASS map (generically
// unique at the optimum). Solve the deduped transportation problem:
// D (~159) distinct classes as columns with capacity = multiplicity.
//  - search sinks at ANY column with spare capacity (earlier sinks)
//  - settling a full column scans all its rows in ONE round (pipelined reads)
//  - common settle path identical to R5 (~210cy: LDS read + packed-key reduce)
// Solver state in registers, 3 rows/cols per lane; wave0 solves after a
// 4-wave fill; dedup tables built once via LDS atomics.

#define BB 128
#define QQ 192
#define CC 512
#define NBIG 1e30f

template<int CTRL>
__device__ __forceinline__ int dpp_mov(int x) {
    return __builtin_amdgcn_update_dpp(x, x, CTRL, 0xf, 0xf, false);
}

__device__ __forceinline__ int readlane_i(int v, int l) {
    return __builtin_amdgcn_readlane(v, l);
}
__device__ __forceinline__ float readlane_f(float v, int l) {
    return __int_as_float(__builtin_amdgcn_readlane(__float_as_int(v), l));
}
__device__ __forceinline__ unsigned umin_(unsigned a, unsigned b) { return a < b ? a : b; }

// fill-phase reduces (validated R1-R6)
__device__ __forceinline__ float wave_max64(float x) {
    x = fmaxf(x, __int_as_float(dpp_mov<0x111>(__float_as_int(x))));
    x = fmaxf(x, __int_as_float(dpp_mov<0x112>(__float_as_int(x))));
    x = fmaxf(x, __int_as_float(dpp_mov<0x114>(__float_as_int(x))));
    x = fmaxf(x, __int_as_float(dpp_mov<0x118>(__float_as_int(x))));
    x = fmaxf(x, __int_as_float(dpp_mov<0x142>(__float_as_int(x))));
    x = fmaxf(x, __int_as_float(dpp_mov<0x143>(__float_as_int(x))));
    return __int_as_float(__builtin_amdgcn_readlane(__float_as_int(x), 63));
}
__device__ __forceinline__ float wave_sum64(float x) {
    x += __int_as_float(dpp_mov<0x111>(__float_as_int(x)));
    x += __int_as_float(dpp_mov<0x112>(__float_as_int(x)));
    x += __int_as_float(dpp_mov<0x114>(__float_as_int(x)));
    x += __int_as_float(dpp_mov<0x118>(__float_as_int(x)));
    x += __int_as_float(dpp_mov<0x142>(__float_as_int(x)));
    x += __int_as_float(dpp_mov<0x143>(__float_as_int(x)));
    return __int_as_float(__builtin_amdgcn_readlane(__float_as_int(x), 63));
}

// packed-key min over 64 lanes: 4 DPP row_shr + 4 readlane + 3 scalar min (R5)
__device__ __forceinline__ unsigned wave_min_pk(unsigned x) {
    x = umin_(x, (unsigned)dpp_mov<0x111>((int)x));
    x = umin_(x, (unsigned)dpp_mov<0x112>((int)x));
    x = umin_(x, (unsigned)dpp_mov<0x114>((int)x));
    x = umin_(x, (unsigned)dpp_mov<0x118>((int)x));
    unsigned a = (unsigned)readlane_i((int)x, 15);
    unsigned b = (unsigned)readlane_i((int)x, 31);
    unsigned c = (unsigned)readlane_i((int)x, 47);
    unsigned d = (unsigned)readlane_i((int)x, 63);
    return umin_(umin_(a, b), umin_(c, d));
}

// distributed-register accessors (idx -> owner lane idx&63, slot idx>>6)
#define GET_I3(a, idx) readlane_i((((idx)>>6)==0) ? a##0 : ((((idx)>>6)==1) ? a##1 : a##2), (idx)&63)
#define GET_F3(a, idx) readlane_f((((idx)>>6)==0) ? a##0 : ((((idx)>>6)==1) ? a##1 : a##2), (idx)&63)
#define SET_I3(a, idx, val) do { const int _s=(idx)>>6, _l=(idx)&63; \
    if (_s==0) { if (lane==_l) a##0=(val); } \
    else if (_s==1) { if (lane==_l) a##1=(val); } \
    else { if (lane==_l) a##2=(val); } } while(0)

__launch_bounds__(256)
__global__ void hungarian_kernel(const float* __restrict__ pred,
                                 const int* __restrict__ targets,
                                 float* __restrict__ ws_part) {
    const int b = blockIdx.x;
    const int lane = threadIdx.x & 63;
    const int wv = threadIdx.x >> 6;

    extern __shared__ float smem[];
    float* cost     = smem;                     // [QQ*QQ] dense cols, stride QQ
    float* spc_lds  = cost + QQ * QQ;           // [QQ] by dense col
    float* lse_lds  = spc_lds + QQ;             // [QQ]
    int*   classd   = (int*)(lse_lds + QQ);     // [QQ] class per dense col
    int*   capd     = classd + QQ;              // [QQ] capacity per dense col
    int*   dorig    = capd + QQ;                // [QQ] dense id per orig col (-1 dup)
    unsigned* tabf  = (unsigned*)(dorig + QQ);  // [CC] first orig col per class
    unsigned* tabc  = tabf + CC;                // [CC] multiplicity per class

    const int t0 = targets[b * QQ + lane];
    const int t1 = targets[b * QQ + lane + 64];
    const int t2 = targets[b * QQ + lane + 128];

    // ---- wave0: dedup tables (one-time) ----
    if (wv == 0) {
        #pragma unroll
        for (int k = 0; k < 8; k++) { tabf[lane + 64 * k] = 0xFFFFFFFFu; tabc[lane + 64 * k] = 0u; }
        __threadfence_block();
        atomicMin(&tabf[t0], (unsigned)lane);
        atomicMin(&tabf[t1], (unsigned)(lane + 64));
        atomicMin(&tabf[t2], (unsigned)(lane + 128));
        atomicAdd(&tabc[t0], 1u);
        atomicAdd(&tabc[t1], 1u);
        atomicAdd(&tabc[t2], 1u);
        __threadfence_block();
        const unsigned fo0 = tabf[t0], fo1 = tabf[t1], fo2 = tabf[t2];
        const int isf0 = (fo0 == (unsigned)lane);
        const int isf1 = (fo1 == (unsigned)(lane + 64));
        const int isf2 = (fo2 == (unsigned)(lane + 128));
        const unsigned long long F0 = __ballot(isf0), F1 = __ballot(isf1), F2 = __ballot(isf2);
        const unsigned long long below = (1ull << lane) - 1ull;
        const int n0 = __popcll(F0), n1 = __popcll(F1);
        const int d0 = isf0 ? __popcll(F0 & below) : -1;
        const int d1 = isf1 ? n0 + __popcll(F1 & below) : -1;
        const int d2 = isf2 ? n0 + n1 + __popcll(F2 & below) : -1;
        dorig[lane] = d0; dorig[lane + 64] = d1; dorig[lane + 128] = d2;
        if (isf0) { classd[d0] = t0; capd[d0] = (int)tabc[t0]; }
        if (isf1) { classd[d1] = t1; capd[d1] = (int)tabc[t1]; }
        if (isf2) { classd[d2] = t2; capd[d2] = (int)tabc[t2]; }
        // mark dead dense slots' cap: cols d >= D never get capd written; init them
        const int Dtot = n0 + n1 + __popcll(F2);
        for (int d = Dtot + lane; d < QQ; d += 64) { capd[d] = 0; classd[d] = 0; }
    }
    __syncthreads();
    const int dd0 = dorig[lane], dd1 = dorig[lane + 64], dd2 = dorig[lane + 128];

    // ---- fill: 4 waves, 48 rows each; write only first-occurrence cols ----
    const float* predb = pred + (size_t)b * QQ * CC;
    {
        const int q0 = wv * 48, q1 = q0 + 48;
        float x[8];
        #pragma unroll
        for (int k = 0; k < 8; k++) x[k] = predb[(size_t)q0 * CC + lane + 64 * k];
        for (int q = q0; q < q1; q++) {
            const float* row = predb + (size_t)q * CC;
            float g0 = row[t0], g1 = row[t1], g2 = row[t2];
            float xn[8];
            if (q + 1 < q1) {
                const float* nrow = row + CC;
                #pragma unroll
                for (int k = 0; k < 8; k++) xn[k] = nrow[lane + 64 * k];
            }
            float mx = x[0];
            #pragma unroll
            for (int k = 1; k < 8; k++) mx = fmaxf(mx, x[k]);
            mx = wave_max64(mx);
            float s = 0.f;
            #pragma unroll
            for (int k = 0; k < 8; k++) s += expf(x[k] - mx);
            s = wave_sum64(s);
            float lse = mx + logf(s);
            if (lane == 0) lse_lds[q] = lse;
            if (dd0 >= 0) cost[q * QQ + dd0] = -expf(g0 - lse);
            if (dd1 >= 0) cost[q * QQ + dd1] = -expf(g1 - lse);
            if (dd2 >= 0) cost[q * QQ + dd2] = -expf(g2 - lse);
            #pragma unroll
            for (int k = 0; k < 8; k++) x[k] = xn[k];
        }
    }
    __syncthreads();
    if (wv != 0) return;
    // single wave from here: in-wave LDS ordering via waitcnt, no barriers.

    // ---- solver state ----
    float u0 = 0.f, u1 = 0.f, u2 = 0.f;       // row duals
    float v0 = 0.f, v1 = 0.f, v2 = 0.f;       // dense-col duals
    int   xx0 = -1, xx1 = -1, xx2 = -1;       // dense col per row
    const int cap0 = capd[lane], cap1 = capd[lane + 64], cap2 = capd[lane + 128];
    const int dead0 = (cap0 == 0), dead1 = (cap1 == 0), dead2 = (cap2 == 0);
    int lf0 = 0, lf1 = 0, lf2 = 0;            // load per dense col
    int fb0 = !dead0, fb1 = !dead1, fb2 = !dead2;  // free-capacity flag

    for (int cur = 0; cur < QQ; cur++) {
        float spc0 = NBIG, spc1 = NBIG, spc2 = NBIG;
        int   p0 = 0, p1 = 0, p2 = 0;
        int   sc0 = dead0, sc1 = dead1, sc2 = dead2;
        unsigned long long SRm0 = 0, SRm1 = 0, SRm2 = 0;
        unsigned long long P0 = 0, P1 = 0, P2 = 0;  // pending-row masks (uniform)
        {
            const int cs = cur >> 6, cl = cur & 63;
            if (cs == 0) P0 = 1ull << cl; else if (cs == 1) P1 = 1ull << cl; else P2 = 1ull << cl;
        }
        float minVal = 0.f;
        int   sink = -1, rounds = 0;

        while (true) {
            // ---- drain pending rows, <=2 per chunk (reads pipeline) ----
            while (P0 | P1 | P2) {
                int i0;
                if (P0)      { i0 = __ffsll(P0) - 1;       P0 &= P0 - 1; }
                else if (P1) { i0 = 64 + __ffsll(P1) - 1;  P1 &= P1 - 1; }
                else         { i0 = 128 + __ffsll(P2) - 1; P2 &= P2 - 1; }
                int i1 = -1;
                if (P0)      { i1 = __ffsll(P0) - 1;       P0 &= P0 - 1; }
                else if (P1) { i1 = 64 + __ffsll(P1) - 1;  P1 &= P1 - 1; }
                else if (P2) { i1 = 128 + __ffsll(P2) - 1; P2 &= P2 - 1; }

                const float* q0p = cost + i0 * QQ;
                const float ca0 = q0p[lane], cb0 = q0p[lane + 64], cc0 = q0p[lane + 128];
                float ca1, cb1, cc1;
                if (i1 >= 0) {
                    const float* q1p = cost + i1 * QQ;
                    ca1 = q1p[lane]; cb1 = q1p[lane + 64]; cc1 = q1p[lane + 128];
                }
                {   // SR bits (scalar)
                    const int is = i0 >> 6, il = i0 & 63;
                    if (is == 0) SRm0 |= 1ull << il; else if (is == 1) SRm1 |= 1ull << il; else SRm2 |= 1ull << il;
                }
                if (i1 >= 0) {
                    const int is = i1 >> 6, il = i1 & 63;
                    if (is == 0) SRm0 |= 1ull << il; else if (is == 1) SRm1 |= 1ull << il; else SRm2 |= 1ull << il;
                }
                const float fs0 = minVal - GET_F3(u, i0);
                const float sa0 = sc0 ? NBIG : fs0 - v0;
                const float sb0 = sc1 ? NBIG : fs0 - v1;
                const float sd0 = sc2 ? NBIG : fs0 - v2;
                {
                    float r = ca0 + sa0; if (r < spc0) { spc0 = r; p0 = i0; }
                    r = cb0 + sb0;       if (r < spc1) { spc1 = r; p1 = i0; }
                    r = cc0 + sd0;       if (r < spc2) { spc2 = r; p2 = i0; }
                }
                if (i1 >= 0) {
                    const float fs1 = minVal - GET_F3(u, i1);
                    const float sa1 = sc0 ? NBIG : fs1 - v0;
                    const float sb1 = sc1 ? NBIG : fs1 - v1;
                    const float sd1 = sc2 ? NBIG : fs1 - v2;
                    float r = ca1 + sa1; if (r < spc0) { spc0 = r; p0 = i1; }
                    r = cb1 + sb1;       if (r < spc1) { spc1 = r; p1 = i1; }
                    r = cc1 + sd1;       if (r < spc2) { spc2 = r; p2 = i1; }
                }
            }

            // ---- reduce + settle one dense col ----
            const unsigned kp0 = sc0 ? 0xFFFFFFFFu : ((__float_as_uint(spc0 + 1.0f) & 0xFFFFFF00u) | (unsigned)lane);
            const unsigned kp1 = sc1 ? 0xFFFFFFFFu : ((__float_as_uint(spc1 + 1.0f) & 0xFFFFFF00u) | (unsigned)(lane + 64));
            const unsigned kp2 = sc2 ? 0xFFFFFFFFu : ((__float_as_uint(spc2 + 1.0f) & 0xFFFFFF00u) | (unsigned)(lane + 128));
            const unsigned pk = wave_min_pk(umin_(umin_(kp0, kp1), kp2));
            const int j = (int)(pk & 255u);
            const int os = j >> 6, ol = j & 63;
            minVal = readlane_f(os == 0 ? spc0 : (os == 1 ? spc1 : spc2), ol);
            sc0 |= (j == lane); sc1 |= (j == lane + 64); sc2 |= (j == lane + 128);
            const int jfree = readlane_i(os == 0 ? fb0 : (os == 1 ? fb1 : fb2), ol);
            if (jfree || ++rounds > 300) { sink = j; break; }
            // full col: its assigned rows become pending
            P0 = __ballot(xx0 == j); P1 = __ballot(xx1 == j); P2 = __ballot(xx2 == j);
        }

        // ---- dual updates (pre-augment xx) ----
        u0 += (cur == lane) ? minVal : 0.f;
        u1 += (cur == lane + 64) ? minVal : 0.f;
        u2 += (cur == lane + 128) ? minVal : 0.f;
        spc_lds[lane] = spc0; spc_lds[lane + 64] = spc1; spc_lds[lane + 128] = spc2;
        const int g0b = (int)((SRm0 >> lane) & 1ull);
        const int g1b = (int)((SRm1 >> lane) & 1ull);
        const int g2b = (int)((SRm2 >> lane) & 1ull);
        if (g0b && lane != cur)         u0 += minVal - spc_lds[xx0];
        if (g1b && (lane + 64) != cur)  u1 += minVal - spc_lds[xx1];
        if (g2b && (lane + 128) != cur) u2 += minVal - spc_lds[xx2];
        if (sc0 && !dead0) v0 -= (minVal - spc0);
        if (sc1 && !dead1) v1 -= (minVal - spc1);
        if (sc2 && !dead2) v2 -= (minVal - spc2);

        // ---- augment: sink gains one row; intermediate cols net zero ----
        {
            const int sl = sink & 63, ss = sink >> 6;
            if (lane == sl) {
                if (ss == 0)      { lf0++; fb0 = lf0 < cap0; }
                else if (ss == 1) { lf1++; fb1 = lf1 < cap1; }
                else              { lf2++; fb2 = lf2 < cap2; }
            }
        }
        int j2 = sink;
        while (true) {
            const int pj = GET_I3(p, j2);
            const int jold = GET_I3(xx, pj);
            SET_I3(xx, pj, j2);
            if (pj == cur) break;
            j2 = jold;
        }
    }

    // ---- CE partial: sum_r (lse[r] - pred[r][class(x[r])]) ----
    float part = 0.f;
    {
        const int tc0 = classd[xx0], tc1 = classd[xx1], tc2 = classd[xx2];
        part += lse_lds[lane]       - predb[(size_t)lane * CC + tc0];
        part += lse_lds[lane + 64]  - predb[(size_t)(lane + 64) * CC + tc1];
        part += lse_lds[lane + 128] - predb[(size_t)(lane + 128) * CC + tc2];
    }
    part = wave_sum64(part);
    if (lane == 0) ws_part[b] = part;
}

__launch_bounds__(64)
__global__ void reduce_kernel(const float* __restrict__ ws_part,
                              float* __restrict__ out) {
    int lane = threadIdx.x;
    float s = ws_part[lane] + ws_part[lane + 64];
    s = wave_sum64(s);
    if (lane == 0) out[0] = s / (float)(BB * QQ);
}

extern "C" void kernel_launch(void* const* d_in, const int* in_sizes, int n_in,
                              void* d_out, int out_size, void* d_ws, size_t ws_size,
                              hipStream_t stream) {
    const float* pred = (const float*)d_in[0];
    const int* targets = (const int*)d_in[1];
    float* out = (float*)d_out;
    float* ws = (float*)d_ws;

    // cost 36864 + spc 192 + lse 192 floats; classd/capd/dorig 576 ints;
    // tabf/tabc 1024 uints  => 155392 bytes (<= 160 KiB)
    const int lds_bytes = (QQ * QQ + 2 * QQ) * (int)sizeof(float)
                        + 3 * QQ * (int)sizeof(int)
                        + 2 * CC * (int)sizeof(unsigned);

    hipLaunchKernelGGL(hungarian_kernel, dim3(BB), dim3(256), lds_bytes, stream,
                       pred, targets, ws);
    hipLaunchKernelGGL(reduce_kernel, dim3(1), dim3(64), 0, stream, ws, out);
}

// Round 8
// 1108.128 us; speedup vs baseline: 1.0400x; 1.0400x over previous
//
#include <hip/hip_runtime.h>
#include <math.h>

// HungarianLoss: B=128 samples, each a 192x192 LSAP on
// cost[q][j] = -softmax(pred[q])[tgt[j]], then mean CE with matched classes.
//
// R8 = R5 (best: sequential JV shortest augmenting path, zero duals, state in
// registers 3/lane, packed u32 argmin) + NEXT-ROW SPECULATIVE PREFETCH:
//  - the reduce returns (min, 2nd-min) packed keys (DPP minsub, R3-validated
//    dataflow); 2nd-min EXACTLY equals next round's pre-relax minimum
//  - at each round start, prefetch cost row r4c[pred2] (the likely next row);
//    on hit the next relax runs from registers (~130cy vs 210cy); on miss the
//    correct read issues immediately (R5 schedule)
//  - winner selection / spc / duals / tie-breaks byte-identical to R5 ->
//    bit-exact regardless of prediction accuracy

#define BB 128
#define QQ 192
#define CC 512
#define NBIG 1e30f

template<int CTRL>
__device__ __forceinline__ int dpp_mov(int x) {
    return __builtin_amdgcn_update_dpp(x, x, CTRL, 0xf, 0xf, false);
}

__device__ __forceinline__ int readlane_i(int v, int l) {
    return __builtin_amdgcn_readlane(v, l);
}
__device__ __forceinline__ float readlane_f(float v, int l) {
    return __int_as_float(__builtin_amdgcn_readlane(__float_as_int(v), l));
}
__device__ __forceinline__ unsigned umin_(unsigned a, unsigned b) { return a < b ? a : b; }
__device__ __forceinline__ unsigned umax_(unsigned a, unsigned b) { return a > b ? a : b; }

// fill-phase reduces (validated R1-R7)
__device__ __forceinline__ float wave_max64(float x) {
    x = fmaxf(x, __int_as_float(dpp_mov<0x111>(__float_as_int(x))));
    x = fmaxf(x, __int_as_float(dpp_mov<0x112>(__float_as_int(x))));
    x = fmaxf(x, __int_as_float(dpp_mov<0x114>(__float_as_int(x))));
    x = fmaxf(x, __int_as_float(dpp_mov<0x118>(__float_as_int(x))));
    x = fmaxf(x, __int_as_float(dpp_mov<0x142>(__float_as_int(x))));
    x = fmaxf(x, __int_as_float(dpp_mov<0x143>(__float_as_int(x))));
    return __int_as_float(__builtin_amdgcn_readlane(__float_as_int(x), 63));
}
__device__ __forceinline__ float wave_sum64(float x) {
    x += __int_as_float(dpp_mov<0x111>(__float_as_int(x)));
    x += __int_as_float(dpp_mov<0x112>(__float_as_int(x)));
    x += __int_as_float(dpp_mov<0x114>(__float_as_int(x)));
    x += __int_as_float(dpp_mov<0x118>(__float_as_int(x)));
    x += __int_as_float(dpp_mov<0x142>(__float_as_int(x)));
    x += __int_as_float(dpp_mov<0x143>(__float_as_int(x)));
    return __int_as_float(__builtin_amdgcn_readlane(__float_as_int(x), 63));
}

// packed-key (min, 2nd-min) over 64 lanes; both uniform via lane 63.
// Same non-overlapping-partition dataflow as R3's float minsub (exact).
// Keys are unique (index bits), so sb = min over keys \ {winner}.
__device__ __forceinline__ void wave_minsub_pk(unsigned& mn, unsigned& sb) {
#define MSU(CTRL) { \
    unsigned omn = (unsigned)dpp_mov<CTRL>((int)mn); \
    unsigned osb = (unsigned)dpp_mov<CTRL>((int)sb); \
    unsigned lo = umin_(mn, omn), hi = umax_(mn, omn); \
    mn = lo; sb = umin_(umin_(sb, osb), hi); }
    MSU(0x111) MSU(0x112) MSU(0x114) MSU(0x118) MSU(0x142) MSU(0x143)
#undef MSU
    mn = (unsigned)readlane_i((int)mn, 63);
    sb = (unsigned)readlane_i((int)sb, 63);
}

// sign-aware monotonic float->u32 key (R5-validated)
__device__ __forceinline__ unsigned fkey(float f) {
    unsigned b = __float_as_uint(f);
    return b ^ (((unsigned)((int)b >> 31)) | 0x80000000u);
}

// distributed-register accessors (idx -> owner lane idx&63, slot idx>>6)
#define GET_I3(a, idx) readlane_i((((idx)>>6)==0) ? a##0 : ((((idx)>>6)==1) ? a##1 : a##2), (idx)&63)
#define GET_F3(a, idx) readlane_f((((idx)>>6)==0) ? a##0 : ((((idx)>>6)==1) ? a##1 : a##2), (idx)&63)
#define SET_I3(a, idx, val) do { const int _s=(idx)>>6, _l=(idx)&63; \
    if (_s==0) { if (lane==_l) a##0=(val); } \
    else if (_s==1) { if (lane==_l) a##1=(val); } \
    else { if (lane==_l) a##2=(val); } } while(0)

__launch_bounds__(256)
__global__ void hungarian_kernel(const float* __restrict__ pred,
                                 const int* __restrict__ targets,
                                 float* __restrict__ ws_part) {
    const int b = blockIdx.x;
    const int lane = threadIdx.x & 63;
    const int wv = threadIdx.x >> 6;

    extern __shared__ float smem[];
    float* cost    = smem;                   // [QQ*QQ] read-only after fill
    float* spc_lds = cost + QQ * QQ;         // [QQ] per-solve spc dump
    float* lse_lds = spc_lds + QQ;           // [QQ]
    int*   tgt_lds = (int*)(lse_lds + QQ);   // [QQ]

    // ---- targets ----
    const int t0 = targets[b * QQ + lane];
    const int t1 = targets[b * QQ + lane + 64];
    const int t2 = targets[b * QQ + lane + 128];
    if (wv == 0) { tgt_lds[lane] = t0; tgt_lds[lane + 64] = t1; tgt_lds[lane + 128] = t2; }

    // ---- fill: 4 waves, 48 rows each (validated R4/R5) ----
    const float* predb = pred + (size_t)b * QQ * CC;
    {
        const int q0 = wv * 48, q1 = q0 + 48;
        float x[8];
        #pragma unroll
        for (int k = 0; k < 8; k++) x[k] = predb[(size_t)q0 * CC + lane + 64 * k];
        for (int q = q0; q < q1; q++) {
            const float* row = predb + (size_t)q * CC;
            float g0 = row[t0], g1 = row[t1], g2 = row[t2];
            float xn[8];
            if (q + 1 < q1) {
                const float* nrow = row + CC;
                #pragma unroll
                for (int k = 0; k < 8; k++) xn[k] = nrow[lane + 64 * k];
            }
            float mx = x[0];
            #pragma unroll
            for (int k = 1; k < 8; k++) mx = fmaxf(mx, x[k]);
            mx = wave_max64(mx);
            float s = 0.f;
            #pragma unroll
            for (int k = 0; k < 8; k++) s += expf(x[k] - mx);
            s = wave_sum64(s);
            float lse = mx + logf(s);
            if (lane == 0) lse_lds[q] = lse;
            cost[q * QQ + lane]       = -expf(g0 - lse);
            cost[q * QQ + lane + 64]  = -expf(g1 - lse);
            cost[q * QQ + lane + 128] = -expf(g2 - lse);
            #pragma unroll
            for (int k = 0; k < 8; k++) x[k] = xn[k];
        }
    }
    __syncthreads();
    if (wv != 0) return;
    // single wave from here: in-wave LDS ordering via waitcnt, no barriers.

    // ---- solver state: 3 rows + 3 cols per lane ----
    float u0 = 0.f, u1 = 0.f, u2 = 0.f;   // row duals
    float v0 = 0.f, v1 = 0.f, v2 = 0.f;   // col duals
    int   xx0 = -1, xx1 = -1, xx2 = -1;   // col4row
    int   yy0 = -1, yy1 = -1, yy2 = -1;   // row4col

    // ---- sequential JV shortest augmenting path (R5 semantics) ----
    for (int cur = 0; cur < QQ; cur++) {
        float spc0 = NBIG, spc1 = NBIG, spc2 = NBIG;
        int   p0 = 0, p1 = 0, p2 = 0;
        int   sc0 = 0, sc1 = 0, sc2 = 0;
        unsigned long long SRm0 = 0, SRm1 = 0, SRm2 = 0;  // scanned-row masks
        int   i = cur;
        float minVal = 0.f;
        int   sink;
        int   fast = 0;                    // row i's data already in pf regs?
        unsigned pred2 = 0xFFFFFFFFu;      // 2nd-best key from last reduce
        float pfA = 0.f, pfB = 0.f, pfD = 0.f;

        while (true) {
            {   // SR[i] (scalar)
                const int is = i >> 6, il = i & 63;
                if (is == 0)      SRm0 |= 1ull << il;
                else if (is == 1) SRm1 |= 1ull << il;
                else              SRm2 |= 1ull << il;
            }
            // guess for NEXT round: likely winner = pred2 (pre-relax min),
            // so likely next row = r4c[pred2]
            int gn = -3;
            if (pred2 != 0xFFFFFFFFu) {
                const int j2 = (int)(pred2 & 255u);
                gn = GET_I3(yy, j2);
            }
            // obtain current row data
            float cA, cB, cD;
            if (fast) {
                cA = pfA; cB = pfB; cD = pfD;
            } else {
                const float* crow = cost + i * QQ;
                cA = crow[lane]; cB = crow[lane + 64]; cD = crow[lane + 128];
            }
            // issue speculative prefetch of the guessed next row
            {
                const int gl = (gn >= 0) ? gn : 0;
                const float* gp = cost + gl * QQ;
                pfA = gp[lane]; pfB = gp[lane + 64]; pfD = gp[lane + 128];
            }
            const float ui = GET_F3(u, i);   // overlaps read latency

            // relax (R5 exact ordering)
            float rA = ((minVal + cA) - ui) - v0;  rA = sc0 ? NBIG : rA;
            if (rA < spc0) { spc0 = rA; p0 = i; }
            float rB = ((minVal + cB) - ui) - v1;  rB = sc1 ? NBIG : rB;
            if (rB < spc1) { spc1 = rB; p1 = i; }
            float rD = ((minVal + cD) - ui) - v2;  rD = sc2 ? NBIG : rD;
            if (rD < spc2) { spc2 = rD; p2 = i; }

            // packed keys (R5 exact); per-lane (min,2nd) of 3, then wave minsub
            const unsigned pkA = sc0 ? 0xFFFFFFFFu : ((fkey(spc0) & 0xFFFFFF00u) | (unsigned)lane);
            const unsigned pkB = sc1 ? 0xFFFFFFFFu : ((fkey(spc1) & 0xFFFFFF00u) | (unsigned)(lane + 64));
            const unsigned pkD = sc2 ? 0xFFFFFFFFu : ((fkey(spc2) & 0xFFFFFF00u) | (unsigned)(lane + 128));
            const unsigned lo = umin_(pkA, pkB), hi = umax_(pkA, pkB);
            unsigned mn = umin_(lo, pkD);
            unsigned sb = umin_(hi, umax_(lo, pkD));
            wave_minsub_pk(mn, sb);

            const int jstar = (int)(mn & 255u);
            const int os = jstar >> 6, ol = jstar & 63;

            // exact minVal from the winner's spc (R5)
            minVal = readlane_f(os == 0 ? spc0 : (os == 1 ? spc1 : spc2), ol);
            sc0 |= (jstar == lane);
            sc1 |= (jstar == lane + 64);
            sc2 |= (jstar == lane + 128);
            const int rj = readlane_i(os == 0 ? yy0 : (os == 1 ? yy1 : yy2), ol);
            if (rj < 0) { sink = jstar; break; }
            fast = (rj == gn);   // hit: prefetched row is exactly the next row
            i = rj;
            pred2 = sb;          // 2nd of this reduce == next pre-relax min
        }

        // ---- dual updates (R5) ----
        u0 += (cur == lane) ? minVal : 0.f;
        u1 += (cur == lane + 64) ? minVal : 0.f;
        u2 += (cur == lane + 128) ? minVal : 0.f;
        spc_lds[lane] = spc0; spc_lds[lane + 64] = spc1; spc_lds[lane + 128] = spc2;
        const int f0 = (int)((SRm0 >> lane) & 1ull);
        const int f1 = (int)((SRm1 >> lane) & 1ull);
        const int f2 = (int)((SRm2 >> lane) & 1ull);
        if (f0 && lane != cur)         u0 += minVal - spc_lds[xx0];
        if (f1 && (lane + 64) != cur)  u1 += minVal - spc_lds[xx1];
        if (f2 && (lane + 128) != cur) u2 += minVal - spc_lds[xx2];
        if (sc0) v0 -= (minVal - spc0);
        if (sc1) v1 -= (minVal - spc1);
        if (sc2) v2 -= (minVal - spc2);

        // ---- augment along stored path (R5) ----
        int j = sink;
        while (true) {
            const int pj = GET_I3(p, j);
            SET_I3(yy, j, pj);
            const int nj = GET_I3(xx, pj);
            SET_I3(xx, pj, j);
            if (pj == cur) break;
            j = nj;
        }
    }

    // ---- CE partial: sum_r (lse[r] - pred[r][tgt[col4row[r]]]) ----
    float part = 0.f;
    {
        const int tc0 = tgt_lds[xx0], tc1 = tgt_lds[xx1], tc2 = tgt_lds[xx2];
        part += lse_lds[lane]       - predb[(size_t)lane * CC + tc0];
        part += lse_lds[lane + 64]  - predb[(size_t)(lane + 64) * CC + tc1];
        part += lse_lds[lane + 128] - predb[(size_t)(lane + 128) * CC + tc2];
    }
    part = wave_sum64(part);
    if (lane == 0) ws_part[b] = part;
}

__launch_bounds__(64)
__global__ void reduce_kernel(const float* __restrict__ ws_part,
                              float* __restrict__ out) {
    int lane = threadIdx.x;
    float s = ws_part[lane] + ws_part[lane + 64];
    s = wave_sum64(s);
    if (lane == 0) out[0] = s / (float)(BB * QQ);
}

extern "C" void kernel_launch(void* const* d_in, const int* in_sizes, int n_in,
                              void* d_out, int out_size, void* d_ws, size_t ws_size,
                              hipStream_t stream) {
    const float* pred = (const float*)d_in[0];
    const int* targets = (const int*)d_in[1];
    float* out = (float*)d_out;
    float* ws = (float*)d_ws;

    const int lds_bytes = (QQ * QQ + 3 * QQ) * (int)sizeof(float);  // 149760 B

    hipLaunchKernelGGL(hungarian_kernel, dim3(BB), dim3(256), lds_bytes, stream,
                       pred, targets, ws);
    hipLaunchKernelGGL(reduce_kernel, dim3(1), dim3(64), 0, stream, ws, out);
}

// Round 9
// 903.971 us; speedup vs baseline: 1.2748x; 1.2258x over previous
//
#include <hip/hip_runtime.h>
#include <math.h>

// HungarianLoss: B=128 samples, each a 192x192 LSAP on
// cost[q][j] = -softmax(pred[q])[tgt[j]], then mean CE with matched classes.
//
// R9 = R5 (sequential JV shortest augmenting path, zero duals, state in
// registers 3/lane, packed u32 argmin reduce) with the per-round chain cut:
//  - key low byte = row4col[j]+1 (not j): reduce winner directly gives the
//    next row, removing the GET_I3(yy)+readlane from the critical path
//    (unique mid-search: assigned cols have distinct rows; field 0 = sink)
//  - sink not settled (exact: its v-delta is 0 in the reference)
//  - previous winner's settle, exact minVal (ballot+readlane of spc),
//    ui readlane, and sv = (minVal-ui)-v all in the ds_read shadow;
//    post-data chain = add -> fkey -> pack -> umin

#define BB 128
#define QQ 192
#define CC 512
#define NBIG 1e30f

template<int CTRL>
__device__ __forceinline__ int dpp_mov(int x) {
    return __builtin_amdgcn_update_dpp(x, x, CTRL, 0xf, 0xf, false);
}

__device__ __forceinline__ int readlane_i(int v, int l) {
    return __builtin_amdgcn_readlane(v, l);
}
__device__ __forceinline__ float readlane_f(float v, int l) {
    return __int_as_float(__builtin_amdgcn_readlane(__float_as_int(v), l));
}
__device__ __forceinline__ unsigned umin_(unsigned a, unsigned b) { return a < b ? a : b; }

// fill-phase reduces (validated R1-R8)
__device__ __forceinline__ float wave_max64(float x) {
    x = fmaxf(x, __int_as_float(dpp_mov<0x111>(__float_as_int(x))));
    x = fmaxf(x, __int_as_float(dpp_mov<0x112>(__float_as_int(x))));
    x = fmaxf(x, __int_as_float(dpp_mov<0x114>(__float_as_int(x))));
    x = fmaxf(x, __int_as_float(dpp_mov<0x118>(__float_as_int(x))));
    x = fmaxf(x, __int_as_float(dpp_mov<0x142>(__float_as_int(x))));
    x = fmaxf(x, __int_as_float(dpp_mov<0x143>(__float_as_int(x))));
    return __int_as_float(__builtin_amdgcn_readlane(__float_as_int(x), 63));
}
__device__ __forceinline__ float wave_sum64(float x) {
    x += __int_as_float(dpp_mov<0x111>(__float_as_int(x)));
    x += __int_as_float(dpp_mov<0x112>(__float_as_int(x)));
    x += __int_as_float(dpp_mov<0x114>(__float_as_int(x)));
    x += __int_as_float(dpp_mov<0x118>(__float_as_int(x)));
    x += __int_as_float(dpp_mov<0x142>(__float_as_int(x)));
    x += __int_as_float(dpp_mov<0x143>(__float_as_int(x)));
    return __int_as_float(__builtin_amdgcn_readlane(__float_as_int(x), 63));
}

// packed-key min over 64 lanes (R5-validated): 4 DPP row_shr + 4 readlane + s_min
__device__ __forceinline__ unsigned wave_min_pk(unsigned x) {
    x = umin_(x, (unsigned)dpp_mov<0x111>((int)x));
    x = umin_(x, (unsigned)dpp_mov<0x112>((int)x));
    x = umin_(x, (unsigned)dpp_mov<0x114>((int)x));
    x = umin_(x, (unsigned)dpp_mov<0x118>((int)x));
    unsigned a = (unsigned)readlane_i((int)x, 15);
    unsigned b = (unsigned)readlane_i((int)x, 31);
    unsigned c = (unsigned)readlane_i((int)x, 47);
    unsigned d = (unsigned)readlane_i((int)x, 63);
    return umin_(umin_(a, b), umin_(c, d));
}

// sign-aware monotonic float->u32 key (R5-validated)
__device__ __forceinline__ unsigned fkey(float f) {
    unsigned b = __float_as_uint(f);
    return b ^ (((unsigned)((int)b >> 31)) | 0x80000000u);
}

// distributed-register accessors (idx -> owner lane idx&63, slot idx>>6)
#define GET_I3(a, idx) readlane_i((((idx)>>6)==0) ? a##0 : ((((idx)>>6)==1) ? a##1 : a##2), (idx)&63)
#define GET_F3(a, idx) readlane_f((((idx)>>6)==0) ? a##0 : ((((idx)>>6)==1) ? a##1 : a##2), (idx)&63)
#define SET_I3(a, idx, val) do { const int _s=(idx)>>6, _l=(idx)&63; \
    if (_s==0) { if (lane==_l) a##0=(val); } \
    else if (_s==1) { if (lane==_l) a##1=(val); } \
    else { if (lane==_l) a##2=(val); } } while(0)

__launch_bounds__(256)
__global__ void hungarian_kernel(const float* __restrict__ pred,
                                 const int* __restrict__ targets,
                                 float* __restrict__ ws_part) {
    const int b = blockIdx.x;
    const int lane = threadIdx.x & 63;
    const int wv = threadIdx.x >> 6;

    extern __shared__ float smem[];
    float* cost    = smem;                   // [QQ*QQ] read-only after fill
    float* spc_lds = cost + QQ * QQ;         // [QQ] per-solve spc dump
    float* lse_lds = spc_lds + QQ;           // [QQ]
    int*   tgt_lds = (int*)(lse_lds + QQ);   // [QQ]

    // ---- targets ----
    const int t0 = targets[b * QQ + lane];
    const int t1 = targets[b * QQ + lane + 64];
    const int t2 = targets[b * QQ + lane + 128];
    if (wv == 0) { tgt_lds[lane] = t0; tgt_lds[lane + 64] = t1; tgt_lds[lane + 128] = t2; }

    // ---- fill: 4 waves, 48 rows each (validated R4/R5) ----
    const float* predb = pred + (size_t)b * QQ * CC;
    {
        const int q0 = wv * 48, q1 = q0 + 48;
        float x[8];
        #pragma unroll
        for (int k = 0; k < 8; k++) x[k] = predb[(size_t)q0 * CC + lane + 64 * k];
        for (int q = q0; q < q1; q++) {
            const float* row = predb + (size_t)q * CC;
            float g0 = row[t0], g1 = row[t1], g2 = row[t2];
            float xn[8];
            if (q + 1 < q1) {
                const float* nrow = row + CC;
                #pragma unroll
                for (int k = 0; k < 8; k++) xn[k] = nrow[lane + 64 * k];
            }
            float mx = x[0];
            #pragma unroll
            for (int k = 1; k < 8; k++) mx = fmaxf(mx, x[k]);
            mx = wave_max64(mx);
            float s = 0.f;
            #pragma unroll
            for (int k = 0; k < 8; k++) s += expf(x[k] - mx);
            s = wave_sum64(s);
            float lse = mx + logf(s);
            if (lane == 0) lse_lds[q] = lse;
            cost[q * QQ + lane]       = -expf(g0 - lse);
            cost[q * QQ + lane + 64]  = -expf(g1 - lse);
            cost[q * QQ + lane + 128] = -expf(g2 - lse);
            #pragma unroll
            for (int k = 0; k < 8; k++) x[k] = xn[k];
        }
    }
    __syncthreads();
    if (wv != 0) return;
    // single wave from here: in-wave LDS ordering via waitcnt, no barriers.

    // ---- solver state: 3 rows + 3 cols per lane ----
    float u0 = 0.f, u1 = 0.f, u2 = 0.f;   // row duals
    float v0 = 0.f, v1 = 0.f, v2 = 0.f;   // col duals
    int   xx0 = -1, xx1 = -1, xx2 = -1;   // col4row
    int   yy0 = -1, yy1 = -1, yy2 = -1;   // row4col

    // ---- sequential JV shortest augmenting path (R5 semantics) ----
    for (int cur = 0; cur < QQ; cur++) {
        float spc0 = NBIG, spc1 = NBIG, spc2 = NBIG;
        int   p0 = 0, p1 = 0, p2 = 0;
        int   sc0 = 0, sc1 = 0, sc2 = 0;
        unsigned k0 = 0xFFFFFFFFu, k1 = 0xFFFFFFFFu, k2 = 0xFFFFFFFFu;
        unsigned long long SRm0 = 0, SRm1 = 0, SRm2 = 0;  // scanned-row masks
        // row4col fields for this search (yy static within a search)
        const unsigned yf0 = (unsigned)(yy0 + 1);
        const unsigned yf1 = (unsigned)(yy1 + 1);
        const unsigned yf2 = (unsigned)(yy2 + 1);
        int   i = cur;
        float minVal = 0.f;
        int   sink;
        unsigned mn = 0xFFFFFFFFu;   // previous round's winner key (none yet)

        while (true) {
            {   // SR[i] (scalar)
                const int is = i >> 6, il = i & 63;
                if (is == 0)      SRm0 |= 1ull << il;
                else if (is == 1) SRm1 |= 1ull << il;
                else              SRm2 |= 1ull << il;
            }
            // issue the row read (address depends only on i)
            const float* crow = cost + i * QQ;
            const float cA = crow[lane];
            const float cB = crow[lane + 64];
            const float cD = crow[lane + 128];

            // ---- shadow work (under the ds_read latency) ----
            if (mn != 0xFFFFFFFFu) {
                // settle previous winner + recover its exact spc (= minVal)
                const int m0 = (k0 == mn), m1 = (k1 == mn), m2 = (k2 == mn);
                const unsigned long long b0 = __ballot(m0);
                const unsigned long long b1 = __ballot(m1);
                const unsigned long long b2 = __ballot(m2);
                if (b0)      minVal = readlane_f(spc0, __ffsll(b0) - 1);
                else if (b1) minVal = readlane_f(spc1, __ffsll(b1) - 1);
                else         minVal = readlane_f(spc2, __ffsll(b2) - 1);
                sc0 |= m0; sc1 |= m1; sc2 |= m2;
                k0 = m0 ? 0xFFFFFFFFu : k0;
                k1 = m1 ? 0xFFFFFFFFu : k1;
                k2 = m2 ? 0xFFFFFFFFu : k2;
            }
            const float ui = GET_F3(u, i);
            const float fs = minVal - ui;
            const float sv0 = sc0 ? NBIG : fs - v0;
            const float sv1 = sc1 ? NBIG : fs - v1;
            const float sv2 = sc2 ? NBIG : fs - v2;

            // ---- post-data: add -> (spc/p update || key chain) ----
            const float rA = cA + sv0;
            const float rB = cB + sv1;
            const float rD = cD + sv2;
            if (rA < spc0) { spc0 = rA; p0 = i; }
            if (rB < spc1) { spc1 = rB; p1 = i; }
            if (rD < spc2) { spc2 = rD; p2 = i; }
            k0 = umin_(k0, (fkey(rA) & 0xFFFFFF00u) | yf0);
            k1 = umin_(k1, (fkey(rB) & 0xFFFFFF00u) | yf1);
            k2 = umin_(k2, (fkey(rD) & 0xFFFFFF00u) | yf2);

            mn = wave_min_pk(umin_(umin_(k0, k1), k2));
            const int rjf = (int)(mn & 255u);
            if (rjf == 0) {
                // sink: winner unassigned. Recover col + exact minVal; NOT settled
                // (exact: reference's sink v-delta is minVal - spc[sink] = 0).
                const unsigned long long b0 = __ballot(k0 == mn);
                const unsigned long long b1 = __ballot(k1 == mn);
                const unsigned long long b2 = __ballot(k2 == mn);
                int ol;
                if (b0)      { ol = __ffsll(b0) - 1; sink = ol;       minVal = readlane_f(spc0, ol); }
                else if (b1) { ol = __ffsll(b1) - 1; sink = ol + 64;  minVal = readlane_f(spc1, ol); }
                else         { ol = __ffsll(b2) - 1; sink = ol + 128; minVal = readlane_f(spc2, ol); }
                break;
            }
            i = rjf - 1;
        }

        // ---- dual updates (R5) ----
        u0 += (cur == lane) ? minVal : 0.f;
        u1 += (cur == lane + 64) ? minVal : 0.f;
        u2 += (cur == lane + 128) ? minVal : 0.f;
        spc_lds[lane] = spc0; spc_lds[lane + 64] = spc1; spc_lds[lane + 128] = spc2;
        const int f0 = (int)((SRm0 >> lane) & 1ull);
        const int f1 = (int)((SRm1 >> lane) & 1ull);
        const int f2 = (int)((SRm2 >> lane) & 1ull);
        if (f0 && lane != cur)         u0 += minVal - spc_lds[xx0];
        if (f1 && (lane + 64) != cur)  u1 += minVal - spc_lds[xx1];
        if (f2 && (lane + 128) != cur) u2 += minVal - spc_lds[xx2];
        if (sc0) v0 -= (minVal - spc0);
        if (sc1) v1 -= (minVal - spc1);
        if (sc2) v2 -= (minVal - spc2);

        // ---- augment along stored path (R5) ----
        int j = sink;
        while (true) {
            const int pj = GET_I3(p, j);
            SET_I3(yy, j, pj);
            const int nj = GET_I3(xx, pj);
            SET_I3(xx, pj, j);
            if (pj == cur) break;
            j = nj;
        }
    }

    // ---- CE partial: sum_r (lse[r] - pred[r][tgt[col4row[r]]]) ----
    float part = 0.f;
    {
        const int tc0 = tgt_lds[xx0], tc1 = tgt_lds[xx1], tc2 = tgt_lds[xx2];
        part += lse_lds[lane]       - predb[(size_t)lane * CC + tc0];
        part += lse_lds[lane + 64]  - predb[(size_t)(lane + 64) * CC + tc1];
        part += lse_lds[lane + 128] - predb[(size_t)(lane + 128) * CC + tc2];
    }
    part = wave_sum64(part);
    if (lane == 0) ws_part[b] = part;
}

__launch_bounds__(64)
__global__ void reduce_kernel(const float* __restrict__ ws_part,
                              float* __restrict__ out) {
    int lane = threadIdx.x;
    float s = ws_part[lane] + ws_part[lane + 64];
    s = wave_sum64(s);
    if (lane == 0) out[0] = s / (float)(BB * QQ);
}

extern "C" void kernel_launch(void* const* d_in, const int* in_sizes, int n_in,
                              void* d_out, int out_size, void* d_ws, size_t ws_size,
                              hipStream_t stream) {
    const float* pred = (const float*)d_in[0];
    const int* targets = (const int*)d_in[1];
    float* out = (float*)d_out;
    float* ws = (float*)d_ws;

    const int lds_bytes = (QQ * QQ + 3 * QQ) * (int)sizeof(float);  // 149760 B

    hipLaunchKernelGGL(hungarian_kernel, dim3(BB), dim3(256), lds_bytes, stream,
                       pred, targets, ws);
    hipLaunchKernelGGL(reduce_kernel, dim3(1), dim3(64), 0, stream, ws, out);
}